// Round 1
// baseline (223.299 us; speedup 1.0000x reference)
//
#include <hip/hip_runtime.h>
#include <hip/hip_bf16.h>

#define EMB 512
#define RD  64
#define NB  8
#define K1  2048
#define K2  2048

typedef short bf16x8 __attribute__((ext_vector_type(8)));  // 8 bf16 = 4 VGPRs
typedef float f32x4  __attribute__((ext_vector_type(4)));

// emb_scale = 1/sqrt(512); red_scale = 1/8 folded into ra
#define SCALE_B 0.04419417382415922f
#define SCALE_A 0.005524271728019902f

__device__ __forceinline__ float bf16lo_to_f(unsigned int u) {
  union { unsigned int u; float f; } c; c.u = u << 16; return c.f;
}
__device__ __forceinline__ float bf16hi_to_f(unsigned int u) {
  union { unsigned int u; float f; } c; c.u = u & 0xFFFF0000u; return c.f;
}
__device__ __forceinline__ unsigned short f_to_bf16u(float v) {
  union { __hip_bfloat16 h; unsigned short s; } c; c.h = __float2bfloat16(v); return c.s;
}

// ---------------------------------------------------------------------------
// Kernel 0: Rt[n][k] = bf16(R[k][n])  (64 x 512, 64 KB) — B-operand layout.
// ---------------------------------------------------------------------------
__global__ __launch_bounds__(256) void k_prep_rt(
    const float* __restrict__ R, __hip_bfloat16* __restrict__ Rt)
{
  int idx = blockIdx.x * 256 + threadIdx.x;   // 32768 total
  int n = idx >> 9, k = idx & 511;            // coalesced write of Rt[n][k]
  Rt[idx] = __float2bfloat16(R[(size_t)k * RD + n]);
}

// ---------------------------------------------------------------------------
// Kernel 1 v2: projection, 4-way K-split.
// Block = 256 threads = 4 waves, ONE 16-row group per block.
// Wave w computes the K-quarter [w*128, w*128+128) (4 MFMA steps), partial
// C (16x64 fp32) combined through LDS; wave w finalizes output cols w*16..+15.
// 2048 blocks (vs 512 before) -> 4 waves/SIMD; serial chain 16 -> 4 steps;
// depth-2 prefetch. Attacks the latency-bound profile of the old version.
// ---------------------------------------------------------------------------
__global__ __launch_bounds__(256) void k_project(
    const float* __restrict__ A, const float* __restrict__ Bm,
    const __hip_bfloat16* __restrict__ Rt,
    __hip_bfloat16* __restrict__ ra, __hip_bfloat16* __restrict__ rb,
    unsigned char* __restrict__ mask)
{
  const int t = threadIdx.x;
  const int w = t >> 6, lane = t & 63;
  const int m = lane & 15, quad = lane >> 4;
  const int blk = blockIdx.x;                 // 0..2047; >=1024 -> B half
  const bool isB = blk >= 1024;
  const float* __restrict__ src = isB ? Bm : A;
  const int rowbase = (blk & 1023) * 16;      // 16 rows per BLOCK
  const int k0 = w * 128;                     // this wave's K-quarter
  const float4* __restrict__ xp =
      reinterpret_cast<const float4*>(src + (size_t)(rowbase + m) * EMB + k0) + quad * 2;

  f32x4 acc[4] = {{0.f,0.f,0.f,0.f},{0.f,0.f,0.f,0.f},
                  {0.f,0.f,0.f,0.f},{0.f,0.f,0.f,0.f}};
  float nzm = 0.f;

  // depth-2 prefetch across the 4 steps
  float4 x0 = xp[0], x1 = xp[1];
  float4 y0 = xp[8], y1 = xp[9];

  #pragma unroll
  for (int s = 0; s < 4; ++s) {
    float4 p0, p1;                            // prefetch step s+2
    if (s < 2) { p0 = xp[(s + 2) * 8]; p1 = xp[(s + 2) * 8 + 1]; }

    nzm = fmaxf(nzm, fmaxf(fmaxf(fabsf(x0.x), fabsf(x0.y)),
                           fmaxf(fabsf(x0.z), fabsf(x0.w))));
    nzm = fmaxf(nzm, fmaxf(fmaxf(fabsf(x1.x), fabsf(x1.y)),
                           fmaxf(fabsf(x1.z), fabsf(x1.w))));

    union { bf16x8 v; __hip_bfloat16 h[8]; } af;
    af.h[0] = __float2bfloat16(x0.x); af.h[1] = __float2bfloat16(x0.y);
    af.h[2] = __float2bfloat16(x0.z); af.h[3] = __float2bfloat16(x0.w);
    af.h[4] = __float2bfloat16(x1.x); af.h[5] = __float2bfloat16(x1.y);
    af.h[6] = __float2bfloat16(x1.z); af.h[7] = __float2bfloat16(x1.w);

    const int kk = k0 + s * 32;
    #pragma unroll
    for (int nt = 0; nt < 4; ++nt) {
      bf16x8 bf = *reinterpret_cast<const bf16x8*>(
          Rt + (size_t)(nt * 16 + m) * EMB + kk + quad * 8);
      acc[nt] = __builtin_amdgcn_mfma_f32_16x16x32_bf16(af.v, bf, acc[nt], 0, 0, 0);
    }
    x0 = y0; x1 = y1; y0 = p0; y1 = p1;
  }

  // ---- combine the 4 K-partials through LDS ----
  __shared__ f32x4 part[4][4][64];            // [wave][nt][lane], 16 KB
  __shared__ float nz[4][16];
  #pragma unroll
  for (int nt = 0; nt < 4; ++nt) part[w][nt][lane] = acc[nt];

  float v = nzm;
  v = fmaxf(v, __shfl_xor(v, 16));
  v = fmaxf(v, __shfl_xor(v, 32));            // per-row max over this K-quarter
  if (lane < 16) nz[w][lane] = v;
  __syncthreads();

  // wave w finalizes n-tile nt=w
  f32x4 sum = part[0][w][lane];
  sum += part[1][w][lane];
  sum += part[2][w][lane];
  sum += part[3][w][lane];

  const float scale = isB ? SCALE_B : SCALE_A;
  __hip_bfloat16* __restrict__ dst = isB ? rb : ra;
  #pragma unroll
  for (int i = 0; i < 4; ++i) {
    const int r = rowbase + quad * 4 + i;     // C/D row = quad*4+i
    dst[(size_t)r * RD + w * 16 + m] = __float2bfloat16(sum[i] * scale);
  }

  if (isB && w == 0 && lane < 16) {
    float mv = fmaxf(fmaxf(nz[0][lane], nz[1][lane]),
                     fmaxf(nz[2][lane], nz[3][lane]));
    mask[rowbase + lane] = (mv == 0.f) ? 1 : 0;
  }
}

// ---------------------------------------------------------------------------
// Kernel 2 v3 (UNCHANGED this round): single GEMM pass; e-values packed
// 2-per-dword as bf16 (64 VGPRs). Pass 2 = pure store stream.
// ---------------------------------------------------------------------------
__global__ __launch_bounds__(256) void k_scores(
    const __hip_bfloat16* __restrict__ ra, const __hip_bfloat16* __restrict__ rb,
    const unsigned char* __restrict__ mask, const float* __restrict__ bptr,
    float* __restrict__ out)
{
  const int bz = blockIdx.y;
  const int row_base = blockIdx.x * 16;
  const int w = threadIdx.x >> 6, lane = threadIdx.x & 63;
  const int m = lane & 15, quad = lane >> 4;
  const float bias = bptr[0];

  const __hip_bfloat16* __restrict__ raB = ra + ((size_t)bz * K1 + row_base) * RD;
  const __hip_bfloat16* __restrict__ rbB = rb + (size_t)bz * K2 * RD;
  const unsigned char* __restrict__ mk = mask + bz * K2;

  bf16x8 a0 = *reinterpret_cast<const bf16x8*>(raB + m * RD + quad * 8);
  bf16x8 a1 = *reinterpret_cast<const bf16x8*>(raB + m * RD + 32 + quad * 8);

  unsigned int epk[16][4];            // e as packed bf16 pairs (64 VGPRs)
  float sums[4] = {0.f, 0.f, 0.f, 0.f};

  #pragma unroll
  for (int it2 = 0; it2 < 16; ++it2) {
    const int n0 = (it2 * 8 + w) * 16 + m;
    const int n1 = (it2 * 8 + 4 + w) * 16 + m;
    bf16x8 b00 = *reinterpret_cast<const bf16x8*>(rbB + n0 * RD + quad * 8);
    bf16x8 b01 = *reinterpret_cast<const bf16x8*>(rbB + n0 * RD + 32 + quad * 8);
    bf16x8 b10 = *reinterpret_cast<const bf16x8*>(rbB + n1 * RD + quad * 8);
    bf16x8 b11 = *reinterpret_cast<const bf16x8*>(rbB + n1 * RD + 32 + quad * 8);
    f32x4 c0 = {0.f, 0.f, 0.f, 0.f}, c1 = {0.f, 0.f, 0.f, 0.f};
    c0 = __builtin_amdgcn_mfma_f32_16x16x32_bf16(a0, b00, c0, 0, 0, 0);
    c1 = __builtin_amdgcn_mfma_f32_16x16x32_bf16(a0, b10, c1, 0, 0, 0);
    c0 = __builtin_amdgcn_mfma_f32_16x16x32_bf16(a1, b01, c0, 0, 0, 0);
    c1 = __builtin_amdgcn_mfma_f32_16x16x32_bf16(a1, b11, c1, 0, 0, 0);
    const bool k0 = mk[n0] != 0, k1 = mk[n1] != 0;
    #pragma unroll
    for (int i = 0; i < 4; ++i) {
      float v0 = k0 ? 0.f : __expf(c0[i] + bias);
      float v1 = k1 ? 0.f : __expf(c1[i] + bias);
      sums[i] += v0 + v1;
      epk[it2][i] = (unsigned int)f_to_bf16u(v0) |
                    ((unsigned int)f_to_bf16u(v1) << 16);
    }
  }

  #pragma unroll
  for (int i = 0; i < 4; ++i) {
    float v = sums[i];
    v += __shfl_xor(v, 1);
    v += __shfl_xor(v, 2);
    v += __shfl_xor(v, 4);
    v += __shfl_xor(v, 8);
    sums[i] = v;
  }

  __shared__ float partial[4][16];
  __shared__ float rowinv[16];
  if ((lane & 15) == 0) {
    #pragma unroll
    for (int i = 0; i < 4; ++i) partial[w][quad * 4 + i] = sums[i];
  }
  __syncthreads();
  if (threadIdx.x < 16) {
    float tsum = partial[0][threadIdx.x] + partial[1][threadIdx.x] +
                 partial[2][threadIdx.x] + partial[3][threadIdx.x];
    rowinv[threadIdx.x] = 1.0f / tsum;
  }
  __syncthreads();

  float inv[4];
  #pragma unroll
  for (int i = 0; i < 4; ++i) inv[i] = rowinv[quad * 4 + i];

  float* __restrict__ outB = out + ((size_t)bz * K1 + row_base) * K2;
  #pragma unroll
  for (int it2 = 0; it2 < 16; ++it2) {
    const int n0 = (it2 * 8 + w) * 16 + m;
    const int n1 = (it2 * 8 + 4 + w) * 16 + m;
    #pragma unroll
    for (int i = 0; i < 4; ++i) {
      const size_t rowoff = (size_t)(quad * 4 + i) * K2;
      outB[rowoff + n0] = bf16lo_to_f(epk[it2][i]) * inv[i];
      outB[rowoff + n1] = bf16hi_to_f(epk[it2][i]) * inv[i];
    }
  }
}

extern "C" void kernel_launch(void* const* d_in, const int* in_sizes, int n_in,
                              void* d_out, int out_size, void* d_ws, size_t ws_size,
                              hipStream_t stream) {
  const float* A  = (const float*)d_in[0];   // (8, 2048, 512)
  const float* Bm = (const float*)d_in[1];   // (8, 2048, 512)
  const float* R  = (const float*)d_in[2];   // (512, 64)
  const float* bb = (const float*)d_in[3];   // (1,)
  float* out = (float*)d_out;                // (8, 2048, 2048)

  char* ws = (char*)d_ws;
  __hip_bfloat16* ra  = (__hip_bfloat16*)(ws);                         // 2 MB
  __hip_bfloat16* rb  = (__hip_bfloat16*)(ws + (((size_t)2) << 20));   // 2 MB
  __hip_bfloat16* Rt  = (__hip_bfloat16*)(ws + (((size_t)4) << 20));   // 64 KB
  unsigned char*  msk = (unsigned char*) (ws + (((size_t)4) << 20) + 65536); // 16 KB

  k_prep_rt<<<dim3(128), dim3(256), 0, stream>>>(R, Rt);
  k_project<<<dim3(2048), dim3(256), 0, stream>>>(A, Bm, Rt, ra, rb, msk);
  k_scores <<<dim3(K1 / 16, NB), dim3(256), 0, stream>>>(ra, rb, msk, bb, out);
}

// Round 2
// 222.497 us; speedup vs baseline: 1.0036x; 1.0036x over previous
//
#include <hip/hip_runtime.h>
#include <hip/hip_bf16.h>

#define EMB 512
#define RD  64
#define NB  8
#define K1  2048
#define K2  2048

typedef short bf16x8 __attribute__((ext_vector_type(8)));  // 8 bf16 = 4 VGPRs
typedef float f32x4  __attribute__((ext_vector_type(4)));

// emb_scale = 1/sqrt(512); red_scale = 1/8 folded into ra
#define SCALE_B 0.04419417382415922f
#define SCALE_A 0.005524271728019902f

__device__ __forceinline__ float bf16lo_to_f(unsigned int u) {
  union { unsigned int u; float f; } c; c.u = u << 16; return c.f;
}
__device__ __forceinline__ float bf16hi_to_f(unsigned int u) {
  union { unsigned int u; float f; } c; c.u = u & 0xFFFF0000u; return c.f;
}
__device__ __forceinline__ unsigned short f_to_bf16u(float v) {
  union { __hip_bfloat16 h; unsigned short s; } c; c.h = __float2bfloat16(v); return c.s;
}

// ---------------------------------------------------------------------------
// Kernel 1 v3: projection, 4-way K-split, R gathered DIRECTLY from global
// (no k_prep_rt kernel, no Rt workspace round-trip).
// Block = 256 threads = 4 waves, ONE 16-row group per block.
// Wave w computes the K-quarter [w*128, w*128+128) (4 MFMA steps), partial
// C (16x64 fp32) combined through LDS; wave w finalizes output cols w*16..+15.
// B-fragment: lane (m,quad) needs bf16(R[kk+quad*8+j][nt*16+m]), j=0..7 —
// 8 strided dword loads from the 128 KB L2-resident R, converted in-register.
// Values are bitwise-identical to the old Rt path (same RNE cvt).
// ---------------------------------------------------------------------------
__global__ __launch_bounds__(256) void k_project(
    const float* __restrict__ A, const float* __restrict__ Bm,
    const float* __restrict__ R,
    __hip_bfloat16* __restrict__ ra, __hip_bfloat16* __restrict__ rb,
    unsigned char* __restrict__ mask)
{
  const int t = threadIdx.x;
  const int w = t >> 6, lane = t & 63;
  const int m = lane & 15, quad = lane >> 4;
  const int blk = blockIdx.x;                 // 0..2047; >=1024 -> B half
  const bool isB = blk >= 1024;
  const float* __restrict__ src = isB ? Bm : A;
  const int rowbase = (blk & 1023) * 16;      // 16 rows per BLOCK
  const int k0 = w * 128;                     // this wave's K-quarter
  const float4* __restrict__ xp =
      reinterpret_cast<const float4*>(src + (size_t)(rowbase + m) * EMB + k0) + quad * 2;

  f32x4 acc[4] = {{0.f,0.f,0.f,0.f},{0.f,0.f,0.f,0.f},
                  {0.f,0.f,0.f,0.f},{0.f,0.f,0.f,0.f}};
  float nzm = 0.f;

  // depth-2 prefetch across the 4 steps
  float4 x0 = xp[0], x1 = xp[1];
  float4 y0 = xp[8], y1 = xp[9];

  #pragma unroll
  for (int s = 0; s < 4; ++s) {
    float4 p0, p1;                            // prefetch step s+2
    if (s < 2) { p0 = xp[(s + 2) * 8]; p1 = xp[(s + 2) * 8 + 1]; }

    nzm = fmaxf(nzm, fmaxf(fmaxf(fabsf(x0.x), fabsf(x0.y)),
                           fmaxf(fabsf(x0.z), fabsf(x0.w))));
    nzm = fmaxf(nzm, fmaxf(fmaxf(fabsf(x1.x), fabsf(x1.y)),
                           fmaxf(fabsf(x1.z), fabsf(x1.w))));

    union { bf16x8 v; __hip_bfloat16 h[8]; } af;
    af.h[0] = __float2bfloat16(x0.x); af.h[1] = __float2bfloat16(x0.y);
    af.h[2] = __float2bfloat16(x0.z); af.h[3] = __float2bfloat16(x0.w);
    af.h[4] = __float2bfloat16(x1.x); af.h[5] = __float2bfloat16(x1.y);
    af.h[6] = __float2bfloat16(x1.z); af.h[7] = __float2bfloat16(x1.w);

    const int kk = k0 + s * 32;
    #pragma unroll
    for (int nt = 0; nt < 4; ++nt) {
      union { bf16x8 v; __hip_bfloat16 h[8]; } bfu;
      const float* __restrict__ rp = R + (size_t)(kk + quad * 8) * RD + nt * 16 + m;
      #pragma unroll
      for (int j = 0; j < 8; ++j) bfu.h[j] = __float2bfloat16(rp[(size_t)j * RD]);
      acc[nt] = __builtin_amdgcn_mfma_f32_16x16x32_bf16(af.v, bfu.v, acc[nt], 0, 0, 0);
    }
    x0 = y0; x1 = y1; y0 = p0; y1 = p1;
  }

  // ---- combine the 4 K-partials through LDS ----
  __shared__ f32x4 part[4][4][64];            // [wave][nt][lane], 16 KB
  __shared__ float nz[4][16];
  #pragma unroll
  for (int nt = 0; nt < 4; ++nt) part[w][nt][lane] = acc[nt];

  float v = nzm;
  v = fmaxf(v, __shfl_xor(v, 16));
  v = fmaxf(v, __shfl_xor(v, 32));            // per-row max over this K-quarter
  if (lane < 16) nz[w][lane] = v;
  __syncthreads();

  // wave w finalizes n-tile nt=w
  f32x4 sum = part[0][w][lane];
  sum += part[1][w][lane];
  sum += part[2][w][lane];
  sum += part[3][w][lane];

  const float scale = isB ? SCALE_B : SCALE_A;
  __hip_bfloat16* __restrict__ dst = isB ? rb : ra;
  #pragma unroll
  for (int i = 0; i < 4; ++i) {
    const int r = rowbase + quad * 4 + i;     // C/D row = quad*4+i
    dst[(size_t)r * RD + w * 16 + m] = __float2bfloat16(sum[i] * scale);
  }

  if (isB && w == 0 && lane < 16) {
    float mv = fmaxf(fmaxf(nz[0][lane], nz[1][lane]),
                     fmaxf(nz[2][lane], nz[3][lane]));
    mask[rowbase + lane] = (mv == 0.f) ? 1 : 0;
  }
}

// ---------------------------------------------------------------------------
// Kernel 2 v3 (UNCHANGED): single GEMM pass; e-values packed 2-per-dword as
// bf16 (64 VGPRs). Pass 2 = pure store stream.
// ---------------------------------------------------------------------------
__global__ __launch_bounds__(256) void k_scores(
    const __hip_bfloat16* __restrict__ ra, const __hip_bfloat16* __restrict__ rb,
    const unsigned char* __restrict__ mask, const float* __restrict__ bptr,
    float* __restrict__ out)
{
  const int bz = blockIdx.y;
  const int row_base = blockIdx.x * 16;
  const int w = threadIdx.x >> 6, lane = threadIdx.x & 63;
  const int m = lane & 15, quad = lane >> 4;
  const float bias = bptr[0];

  const __hip_bfloat16* __restrict__ raB = ra + ((size_t)bz * K1 + row_base) * RD;
  const __hip_bfloat16* __restrict__ rbB = rb + (size_t)bz * K2 * RD;
  const unsigned char* __restrict__ mk = mask + bz * K2;

  bf16x8 a0 = *reinterpret_cast<const bf16x8*>(raB + m * RD + quad * 8);
  bf16x8 a1 = *reinterpret_cast<const bf16x8*>(raB + m * RD + 32 + quad * 8);

  unsigned int epk[16][4];            // e as packed bf16 pairs (64 VGPRs)
  float sums[4] = {0.f, 0.f, 0.f, 0.f};

  #pragma unroll
  for (int it2 = 0; it2 < 16; ++it2) {
    const int n0 = (it2 * 8 + w) * 16 + m;
    const int n1 = (it2 * 8 + 4 + w) * 16 + m;
    bf16x8 b00 = *reinterpret_cast<const bf16x8*>(rbB + n0 * RD + quad * 8);
    bf16x8 b01 = *reinterpret_cast<const bf16x8*>(rbB + n0 * RD + 32 + quad * 8);
    bf16x8 b10 = *reinterpret_cast<const bf16x8*>(rbB + n1 * RD + quad * 8);
    bf16x8 b11 = *reinterpret_cast<const bf16x8*>(rbB + n1 * RD + 32 + quad * 8);
    f32x4 c0 = {0.f, 0.f, 0.f, 0.f}, c1 = {0.f, 0.f, 0.f, 0.f};
    c0 = __builtin_amdgcn_mfma_f32_16x16x32_bf16(a0, b00, c0, 0, 0, 0);
    c1 = __builtin_amdgcn_mfma_f32_16x16x32_bf16(a0, b10, c1, 0, 0, 0);
    c0 = __builtin_amdgcn_mfma_f32_16x16x32_bf16(a1, b01, c0, 0, 0, 0);
    c1 = __builtin_amdgcn_mfma_f32_16x16x32_bf16(a1, b11, c1, 0, 0, 0);
    const bool k0 = mk[n0] != 0, k1 = mk[n1] != 0;
    #pragma unroll
    for (int i = 0; i < 4; ++i) {
      float v0 = k0 ? 0.f : __expf(c0[i] + bias);
      float v1 = k1 ? 0.f : __expf(c1[i] + bias);
      sums[i] += v0 + v1;
      epk[it2][i] = (unsigned int)f_to_bf16u(v0) |
                    ((unsigned int)f_to_bf16u(v1) << 16);
    }
  }

  #pragma unroll
  for (int i = 0; i < 4; ++i) {
    float v = sums[i];
    v += __shfl_xor(v, 1);
    v += __shfl_xor(v, 2);
    v += __shfl_xor(v, 4);
    v += __shfl_xor(v, 8);
    sums[i] = v;
  }

  __shared__ float partial[4][16];
  __shared__ float rowinv[16];
  if ((lane & 15) == 0) {
    #pragma unroll
    for (int i = 0; i < 4; ++i) partial[w][quad * 4 + i] = sums[i];
  }
  __syncthreads();
  if (threadIdx.x < 16) {
    float tsum = partial[0][threadIdx.x] + partial[1][threadIdx.x] +
                 partial[2][threadIdx.x] + partial[3][threadIdx.x];
    rowinv[threadIdx.x] = 1.0f / tsum;
  }
  __syncthreads();

  float inv[4];
  #pragma unroll
  for (int i = 0; i < 4; ++i) inv[i] = rowinv[quad * 4 + i];

  float* __restrict__ outB = out + ((size_t)bz * K1 + row_base) * K2;
  #pragma unroll
  for (int it2 = 0; it2 < 16; ++it2) {
    const int n0 = (it2 * 8 + w) * 16 + m;
    const int n1 = (it2 * 8 + 4 + w) * 16 + m;
    #pragma unroll
    for (int i = 0; i < 4; ++i) {
      const size_t rowoff = (size_t)(quad * 4 + i) * K2;
      outB[rowoff + n0] = bf16lo_to_f(epk[it2][i]) * inv[i];
      outB[rowoff + n1] = bf16hi_to_f(epk[it2][i]) * inv[i];
    }
  }
}

extern "C" void kernel_launch(void* const* d_in, const int* in_sizes, int n_in,
                              void* d_out, int out_size, void* d_ws, size_t ws_size,
                              hipStream_t stream) {
  const float* A  = (const float*)d_in[0];   // (8, 2048, 512)
  const float* Bm = (const float*)d_in[1];   // (8, 2048, 512)
  const float* R  = (const float*)d_in[2];   // (512, 64)
  const float* bb = (const float*)d_in[3];   // (1,)
  float* out = (float*)d_out;                // (8, 2048, 2048)

  char* ws = (char*)d_ws;
  __hip_bfloat16* ra  = (__hip_bfloat16*)(ws);                         // 2 MB
  __hip_bfloat16* rb  = (__hip_bfloat16*)(ws + (((size_t)2) << 20));   // 2 MB
  unsigned char*  msk = (unsigned char*) (ws + (((size_t)4) << 20));   // 16 KB

  k_project<<<dim3(2048), dim3(256), 0, stream>>>(A, Bm, R, ra, rb, msk);
  k_scores <<<dim3(K1 / 16, NB), dim3(256), 0, stream>>>(ra, rb, msk, bb, out);
}